// Round 3
// baseline (152.410 us; speedup 1.0000x reference)
//
#include <hip/hip_runtime.h>
#include <math.h>

// NetVLAD clustering layer, f32, MI355X — 3 kernels.
// x:[16,256,1500], centroids:[64,256], lin_w:[66,256], lin_b:[66]
// out: [16, 64*256] f32
//
// KA (chunk,u) 512 thr, 1 block/CU: stage x chunk (96 t) -> LDS; logits with
//     W via wave-uniform SCALAR loads (no LDS for W, no staging barriers);
//     two 4-wave t-groups, f-quarter split, LDS tree reduce; softmax -> Asm;
//     per-wave 8c x (lane,4f) aggregation with folded asum.
// KB (c,u): reduce 16 chunk-partials, subtract asum*centroid, intra-norm.
// KC: global L2 scale (float4).

#define NU 16
#define NF 256
#define NT 1500
#define NC 64
#define NCG 66          // clusters + ghosts
#define EPSN 1e-12f
#define TCH 96          // t-chunk (16 chunks cover 1536 >= 1500)
#define NCHUNK 16
#define XP 98           // LDS row stride: even (8B-aligned rows for float2),
                        // bank stride 2 -> 2-way aliasing (free per m136)

__device__ __forceinline__ float blk_reduce_sum(float v, float* sbuf) {
    #pragma unroll
    for (int off = 32; off > 0; off >>= 1) v += __shfl_down(v, off, 64);
    const int lane = threadIdx.x & 63, wv = threadIdx.x >> 6;
    if (lane == 0) sbuf[wv] = v;
    __syncthreads();
    float r = sbuf[0] + sbuf[1] + sbuf[2] + sbuf[3];
    __syncthreads();
    return r;
}

// ---------------- KA: logits + softmax + per-chunk aggregation ----------------
__global__ __launch_bounds__(512, 2) void ka_fused(
        const float* __restrict__ x, const float* __restrict__ lin_w,
        const float* __restrict__ lin_b, float* __restrict__ partial,
        float* __restrict__ asum_part) {
    __shared__ float Xsm[NF][XP];          // 100,352 B  [f][t]
    __shared__ float Asm[NC][XP];          //  25,088 B  [c][t]
    __shared__ float red[2][NCG][64];      //  33,792 B  per-group reduce
    // total 159,232 B -> 1 block/CU, 8 waves/CU

    const int chunk = blockIdx.x, u = blockIdx.y;
    const int tid  = threadIdx.x;
    const int lane = tid & 63;
    const int wave = tid >> 6;
    const int t0 = chunk * TCH;

    // ---- stage X chunk -> LDS (zero-fill past NT) ----
    {
        const int fr = tid >> 3;           // 0..63
        const int ks = (tid & 7) * 4;      // 0,4,...,28
        #pragma unroll
        for (int r = 0; r < 4; ++r) {
            const int f = fr + 64 * r;
            const float* rp = x + (size_t)(u * NF + f) * NT + t0;
            #pragma unroll
            for (int q = 0; q < 3; ++q) {
                const int kk = ks + 32 * q;
                const int tg = t0 + kk;
                float4 v;
                if (tg + 3 < NT) v = *(const float4*)(rp + kk);  // 16B-aligned
                else {
                    v.x = (tg + 0 < NT) ? rp[kk + 0] : 0.0f;
                    v.y = (tg + 1 < NT) ? rp[kk + 1] : 0.0f;
                    v.z = (tg + 2 < NT) ? rp[kk + 2] : 0.0f;
                    v.w = (tg + 3 < NT) ? rp[kk + 3] : 0.0f;
                }
                *(float2*)&Xsm[f][kk]     = make_float2(v.x, v.y);  // rows 8B-aligned
                *(float2*)&Xsm[f][kk + 2] = make_float2(v.z, v.w);
            }
        }
    }
    __syncthreads();

    // ---- logits: group (waves 0-3 / 4-7) x f-quarter split ----
    // group 0: t-col = lane (cols 0..63); group 1: t-col = 64+(lane&31)
    // (lanes 32-63 duplicate lanes 0-31; only 6% waste block-wide).
    const int grp  = wave >> 2;
    const int wq   = __builtin_amdgcn_readfirstlane(wave & 3);  // uniform f-quarter
    const int tcol = grp ? (64 + (lane & 31)) : lane;

    float acc[NCG];
    #pragma unroll
    for (int c = 0; c < NCG; ++c) acc[c] = 0.0f;

    #pragma unroll
    for (int fc = 0; fc < 4; ++fc) {
        const int fbase = wq * 64 + fc * 16;     // uniform -> W loads scalarize
        float xv[16];
        #pragma unroll
        for (int k = 0; k < 16; ++k) xv[k] = Xsm[fbase + k][tcol];
        #pragma unroll
        for (int c = 0; c < NCG; ++c) {
            const float4* wp = (const float4*)(lin_w + c * NF + fbase);
            const float4 w0 = wp[0], w1 = wp[1], w2 = wp[2], w3 = wp[3];
            acc[c] += w0.x*xv[0]  + w0.y*xv[1]  + w0.z*xv[2]  + w0.w*xv[3]
                    + w1.x*xv[4]  + w1.y*xv[5]  + w1.z*xv[6]  + w1.w*xv[7]
                    + w2.x*xv[8]  + w2.y*xv[9]  + w2.z*xv[10] + w2.w*xv[11]
                    + w3.x*xv[12] + w3.y*xv[13] + w3.z*xv[14] + w3.w*xv[15];
        }
    }

    // ---- cross-wave reduce within each group (P0+P1+P2+P3) ----
    {
        float (*redg)[64] = red[grp];
        if (wq == 3) {
            #pragma unroll
            for (int c = 0; c < NCG; ++c) redg[c][lane] = acc[c];
        }
        __syncthreads();
        if (wq == 1) {
            #pragma unroll
            for (int c = 0; c < NCG; ++c) acc[c] += redg[c][lane];
        }
        __syncthreads();
        if (wq == 2) {
            #pragma unroll
            for (int c = 0; c < NCG; ++c) redg[c][lane] = acc[c];
        }
        __syncthreads();
        if (wq == 0) {
            #pragma unroll
            for (int c = 0; c < NCG; ++c) acc[c] += redg[c][lane];
        }
        __syncthreads();
        if (wq == 1) {
            #pragma unroll
            for (int c = 0; c < NCG; ++c) redg[c][lane] = acc[c];
        }
        __syncthreads();
        if (wq == 0) {
            #pragma unroll
            for (int c = 0; c < NCG; ++c) acc[c] += redg[c][lane] + lin_b[c];
            // softmax over 66, keep 64
            float m = -INFINITY;
            #pragma unroll
            for (int c = 0; c < NCG; ++c) m = fmaxf(m, acc[c]);
            float s = 0.0f;
            #pragma unroll
            for (int c = 0; c < NCG; ++c) { acc[c] = __expf(acc[c] - m); s += acc[c]; }
            const int t = t0 + tcol;
            const float sc = (t < NT) ? (1.0f / s) : 0.0f;   // zero padded t's
            if (grp == 0) {
                #pragma unroll
                for (int c = 0; c < NC; ++c) Asm[c][lane] = acc[c] * sc;
            } else if (lane < 32) {
                #pragma unroll
                for (int c = 0; c < NC; ++c) Asm[c][64 + lane] = acc[c] * sc;
            }
        }
        __syncthreads();
    }

    // ---- aggregation: wave -> 8 c's, lane -> 4 f's (f = lane + 64j) ----
    {
        const int cb = wave * 8;
        float ag[8][4], as[8];
        #pragma unroll
        for (int i = 0; i < 8; ++i) {
            as[i] = 0.0f;
            #pragma unroll
            for (int j = 0; j < 4; ++j) ag[i][j] = 0.0f;
        }

        #pragma unroll 4
        for (int k = 0; k < TCH; k += 2) {
            float2 av[8], xv2[4];
            #pragma unroll
            for (int i = 0; i < 8; ++i) av[i] = *(const float2*)&Asm[cb + i][k];   // broadcast
            #pragma unroll
            for (int j = 0; j < 4; ++j) xv2[j] = *(const float2*)&Xsm[lane + 64 * j][k];
            #pragma unroll
            for (int i = 0; i < 8; ++i) {
                as[i] += av[i].x + av[i].y;
                #pragma unroll
                for (int j = 0; j < 4; ++j)
                    ag[i][j] += av[i].x * xv2[j].x + av[i].y * xv2[j].y;
            }
        }

        #pragma unroll
        for (int i = 0; i < 8; ++i) {
            float* op = partial + ((size_t)((chunk * NU + u) * NC + cb + i)) * NF;
            #pragma unroll
            for (int j = 0; j < 4; ++j) op[lane + 64 * j] = ag[i][j];  // 256B coalesced
        }
        if (lane == 0) {
            #pragma unroll
            for (int i = 0; i < 8; ++i)
                asum_part[(chunk * NU + u) * NC + cb + i] = as[i];
        }
    }
}

// ---------------- KB: reduce partials + intra-normalize ----------------
__global__ __launch_bounds__(256) void kb_norm(
        const float* __restrict__ asum_part, const float* __restrict__ partial,
        const float* __restrict__ centroids, float* __restrict__ compn,
        float* __restrict__ rowsq) {
    const int c = blockIdx.x, u = blockIdx.y;
    const int tid = threadIdx.x;
    __shared__ float sbuf[4];

    float asum = 0.0f;                   // uniform -> scalar loads
    #pragma unroll
    for (int ch = 0; ch < NCHUNK; ++ch)
        asum += asum_part[(ch * NU + u) * NC + c];

    float val = 0.0f;
    #pragma unroll
    for (int ch = 0; ch < NCHUNK; ++ch)
        val += partial[((size_t)((ch * NU + u) * NC + c)) * NF + tid];
    val -= asum * centroids[c * NF + tid];

    const float ss = blk_reduce_sum(val * val, sbuf);
    const float d  = fmaxf(sqrtf(ss), EPSN);
    compn[((size_t)(u * NC + c)) * NF + tid] = val / d;
    if (tid == 0) rowsq[u * NC + c] = ss / (d * d);
}

// ---------------- KC: global normalize ----------------
__global__ __launch_bounds__(256) void kc_scale(
        const float* __restrict__ compn, const float* __restrict__ rowsq,
        float* __restrict__ out) {
    const int u = blockIdx.y, sl = blockIdx.x;
    const int tid = threadIdx.x;
    float g = 0.0f;                      // uniform -> scalar loads
    #pragma unroll
    for (int c = 0; c < NC; ++c) g += rowsq[u * NC + c];
    const float inv = 1.0f / fmaxf(sqrtf(g), EPSN);
    const int base = u * (NC * NF) + sl * 1024 + tid * 4;
    float4 v = *(const float4*)(compn + base);
    v.x *= inv; v.y *= inv; v.z *= inv; v.w *= inv;
    *(float4*)(out + base) = v;
}

// ---------------- launcher ----------------
extern "C" void kernel_launch(void* const* d_in, const int* in_sizes, int n_in,
                              void* d_out, int out_size, void* d_ws, size_t ws_size,
                              hipStream_t stream) {
    (void)in_sizes; (void)n_in; (void)out_size; (void)ws_size;
    const float* x         = (const float*)d_in[0];
    const float* centroids = (const float*)d_in[1];
    const float* lin_w     = (const float*)d_in[2];
    const float* lin_b     = (const float*)d_in[3];
    float* out = (float*)d_out;

    float* ws        = (float*)d_ws;
    float* partial   = ws;                                        // 16*16*64*256 = 4,194,304 f
    float* asum_part = partial + (size_t)NCHUNK * NU * NC * NF;   // 16*16*64 = 16,384 f
    float* compn     = asum_part + NCHUNK * NU * NC;              // 262,144 f
    float* rowsq     = compn + (size_t)NU * NC * NF;              // 1,024 f (~17.9 MB)

    hipLaunchKernelGGL(ka_fused, dim3(NCHUNK, NU), dim3(512), 0, stream,
                       x, lin_w, lin_b, partial, asum_part);
    hipLaunchKernelGGL(kb_norm,  dim3(NC, NU), dim3(256), 0, stream,
                       asum_part, partial, centroids, compn, rowsq);
    hipLaunchKernelGGL(kc_scale, dim3(16, NU), dim3(256), 0, stream,
                       compn, rowsq, out);
}